// Round 1
// baseline (2297.166 us; speedup 1.0000x reference)
//
#include <hip/hip_runtime.h>

#define EMB 768
#define NK  8192
#define NB  16384

#define BM 128
#define BN 128
#define BK 32
#define LDT 132   // BM + 4 pad: keeps rows 16B-aligned (132*4=528=33*16) and breaks bank conflicts

// ---------------- codebook inverse norms ----------------
__global__ void codebook_norms_k(const float* __restrict__ C, float* __restrict__ rn){
  __shared__ float red[256];
  const int r = blockIdx.x;
  const int tid = threadIdx.x;
  const float* row = C + (size_t)r * EMB;
  float s = 0.f;
  for (int c = tid; c < EMB; c += 256){ float v = row[c]; s = fmaf(v, v, s); }
  red[tid] = s; __syncthreads();
  for (int off = 128; off > 0; off >>= 1){
    if (tid < off) red[tid] += red[tid + off];
    __syncthreads();
  }
  if (tid == 0){
    float n = sqrtf(red[0]);
    rn[r] = 1.0f / fmaxf(n, 1e-8f);
  }
}

// monotonic order-preserving encoding of float into uint
__device__ __forceinline__ unsigned int fenc(float v){
  unsigned int u = __float_as_uint(v);
  return (u & 0x80000000u) ? ~u : (u | 0x80000000u);
}

// ---------------- fused GEMM + argmax ----------------
// C[b,k]-tile = X-tile * Cb-tile^T over d; scale col k by rn[k]; argmax over k
// per row via packed atomicMax (max val, then min index on ties == jnp.argmax).
__global__ __launch_bounds__(256, 2)
void gemm_argmax_k(const float* __restrict__ X, const float* __restrict__ Cb,
                   const float* __restrict__ rn, unsigned long long* __restrict__ keys){
  __shared__ float Xs[BK][LDT];
  __shared__ float Cs[BK][LDT];
  const int tid = threadIdx.x;
  const int tx = tid & 15;        // col group
  const int ty = tid >> 4;        // row group
  const int m0 = blockIdx.y * BM;
  const int n0 = blockIdx.x * BN;

  float acc[2][2][4][4];
  #pragma unroll
  for (int a = 0; a < 2; ++a)
    #pragma unroll
    for (int b = 0; b < 2; ++b)
      #pragma unroll
      for (int i = 0; i < 4; ++i)
        #pragma unroll
        for (int j = 0; j < 4; ++j)
          acc[a][b][i][j] = 0.f;

  const int lr = tid >> 3;          // 0..31
  const int lc = (tid & 7) * 4;     // 0,4,..,28

  for (int k0 = 0; k0 < EMB; k0 += BK){
    #pragma unroll
    for (int l = 0; l < 4; ++l){
      const int r = lr + 32 * l;
      const float4 vx = *(const float4*)(X  + (size_t)(m0 + r) * EMB + k0 + lc);
      const float4 vc = *(const float4*)(Cb + (size_t)(n0 + r) * EMB + k0 + lc);
      Xs[lc + 0][r] = vx.x; Xs[lc + 1][r] = vx.y; Xs[lc + 2][r] = vx.z; Xs[lc + 3][r] = vx.w;
      Cs[lc + 0][r] = vc.x; Cs[lc + 1][r] = vc.y; Cs[lc + 2][r] = vc.z; Cs[lc + 3][r] = vc.w;
    }
    __syncthreads();
    #pragma unroll
    for (int k = 0; k < BK; ++k){
      const float4 a0 = *(const float4*)&Xs[k][ty * 4];
      const float4 a1 = *(const float4*)&Xs[k][ty * 4 + 64];
      const float4 b0 = *(const float4*)&Cs[k][tx * 4];
      const float4 b1 = *(const float4*)&Cs[k][tx * 4 + 64];
      const float av[2][4] = {{a0.x,a0.y,a0.z,a0.w},{a1.x,a1.y,a1.z,a1.w}};
      const float bv[2][4] = {{b0.x,b0.y,b0.z,b0.w},{b1.x,b1.y,b1.z,b1.w}};
      #pragma unroll
      for (int ih = 0; ih < 2; ++ih)
        #pragma unroll
        for (int i = 0; i < 4; ++i)
          #pragma unroll
          for (int jh = 0; jh < 2; ++jh)
            #pragma unroll
            for (int j = 0; j < 4; ++j)
              acc[ih][jh][i][j] = fmaf(av[ih][i], bv[jh][j], acc[ih][jh][i][j]);
    }
    __syncthreads();
  }

  // scale by codebook inverse norms, then per-row argmax
  float rnv[2][4];
  #pragma unroll
  for (int jh = 0; jh < 2; ++jh)
    #pragma unroll
    for (int j = 0; j < 4; ++j)
      rnv[jh][j] = rn[n0 + jh * 64 + tx * 4 + j];

  #pragma unroll
  for (int ih = 0; ih < 2; ++ih){
    #pragma unroll
    for (int i = 0; i < 4; ++i){
      float bval = -3.0e38f; int bidx = 1 << 30;
      #pragma unroll
      for (int jh = 0; jh < 2; ++jh){
        #pragma unroll
        for (int j = 0; j < 4; ++j){
          const float s = acc[ih][jh][i][j] * rnv[jh][j];
          const int nl = jh * 64 + tx * 4 + j;   // ascending within thread
          if (s > bval){ bval = s; bidx = nl; }  // strictly greater -> first index
        }
      }
      // butterfly across the 16 tx lanes (consecutive lanes in the wave)
      #pragma unroll
      for (int off = 1; off < 16; off <<= 1){
        const float sv = __shfl_xor(bval, off);
        const int   si = __shfl_xor(bidx, off);
        if (sv > bval || (sv == bval && si < bidx)){ bval = sv; bidx = si; }
      }
      if (tx == 0){
        const int m  = m0 + ih * 64 + ty * 4 + i;
        const int gn = n0 + bidx;
        const unsigned long long key =
            ((unsigned long long)fenc(bval) << 32) | (unsigned int)(8191 - gn);
        atomicMax(&keys[m], key);
      }
    }
  }
}

// ---------------- gather + output + per-row loss ----------------
__global__ void writer_k(const float* __restrict__ X, const float* __restrict__ Cb,
                         const unsigned long long* __restrict__ keys,
                         float* __restrict__ out, float* __restrict__ rowloss){
  __shared__ float red[256];
  const int r = blockIdx.x;
  const int tid = threadIdx.x;
  const int idx = 8191 - (int)(unsigned int)(keys[r] & 0xFFFFFFFFull);
  const float* q = Cb + (size_t)idx * EMB;
  const float* x = X + (size_t)r * EMB;
  float* o = out + (size_t)r * EMB;
  float s = 0.f;
  for (int c = tid; c < EMB; c += 256){
    const float qv = q[c], xv = x[c];
    const float d = qv - xv;
    o[c] = xv + d;            // matches reference's inputs + (quantized - inputs)
    s = fmaf(d, d, s);
  }
  red[tid] = s; __syncthreads();
  for (int off = 128; off > 0; off >>= 1){
    if (tid < off) red[tid] += red[tid + off];
    __syncthreads();
  }
  if (tid == 0) rowloss[r] = red[0];
}

// ---------------- deterministic loss finalize ----------------
__global__ void finalize_k(const float* __restrict__ rowloss, float* __restrict__ loss_out){
  __shared__ double red[256];
  const int tid = threadIdx.x;
  double s = 0.0;
  for (int i = tid; i < NB; i += 256) s += (double)rowloss[i];
  red[tid] = s; __syncthreads();
  for (int off = 128; off > 0; off >>= 1){
    if (tid < off) red[tid] += red[tid + off];
    __syncthreads();
  }
  if (tid == 0)
    loss_out[0] = (float)(1.25 * red[0] / ((double)NB * (double)EMB));
}

extern "C" void kernel_launch(void* const* d_in, const int* in_sizes, int n_in,
                              void* d_out, int out_size, void* d_ws, size_t ws_size,
                              hipStream_t stream){
  const float* X  = (const float*)d_in[0];
  const float* Cb = (const float*)d_in[1];
  float* out = (float*)d_out;

  char* ws = (char*)d_ws;
  unsigned long long* keys = (unsigned long long*)ws;          // 16384*8   = 131072 B
  float* rn      = (float*)(ws + 131072);                      //  8192*4   =  32768 B
  float* rowloss = (float*)(ws + 131072 + 32768);              // 16384*4   =  65536 B

  hipMemsetAsync(keys, 0, (size_t)NB * 8, stream);             // 0 < fenc(any sim) sentinel
  codebook_norms_k<<<NK, 256, 0, stream>>>(Cb, rn);
  gemm_argmax_k<<<dim3(NK / BN, NB / BM), 256, 0, stream>>>(X, Cb, rn, keys);
  writer_k<<<NB, 256, 0, stream>>>(X, Cb, keys, out, rowloss);
  finalize_k<<<1, 256, 0, stream>>>(rowloss, out + (size_t)NB * EMB);
}

// Round 2
// 824.169 us; speedup vs baseline: 2.7873x; 2.7873x over previous
//
#include <hip/hip_runtime.h>

#define EMB 768
#define NK  8192
#define NB  16384
#define NBLK 512            // NK/16 col-blocks per row
#define MARGIN 0.10f        // scaled-sim margin: ~28 sigma of bf16 screening error

typedef __attribute__((ext_vector_type(8))) __bf16 bf16x8;
typedef __attribute__((ext_vector_type(4))) float f32x4;

// ---------------- fp32 -> bf16 (RTNE) ----------------
__device__ __forceinline__ unsigned short f2bf(float f){
  unsigned u = __float_as_uint(f);
  u += 0x7FFFu + ((u >> 16) & 1u);
  return (unsigned short)(u >> 16);
}

__global__ void convert_k(const float* __restrict__ in, unsigned short* __restrict__ out, int n4){
  int i = blockIdx.x * blockDim.x + threadIdx.x;
  if (i < n4){
    float4 v = *(const float4*)(in + (size_t)i * 4);
    ushort4 o;
    o.x = f2bf(v.x); o.y = f2bf(v.y); o.z = f2bf(v.z); o.w = f2bf(v.w);
    *(ushort4*)(out + (size_t)i * 4) = o;
  }
}

// ---------------- codebook inverse norms ----------------
__global__ void codebook_norms_k(const float* __restrict__ C, float* __restrict__ rn){
  __shared__ float red[256];
  const int r = blockIdx.x;
  const int tid = threadIdx.x;
  const float* row = C + (size_t)r * EMB;
  float s = 0.f;
  for (int c = tid; c < EMB; c += 256){ float v = row[c]; s = fmaf(v, v, s); }
  red[tid] = s; __syncthreads();
  for (int off = 128; off > 0; off >>= 1){
    if (tid < off) red[tid] += red[tid + off];
    __syncthreads();
  }
  if (tid == 0){
    float n = sqrtf(red[0]);
    rn[r] = 1.0f / fmaxf(n, 1e-8f);
  }
}

// ---------------- bf16 MFMA GEMM + per-16col blockmax ----------------
// 128x128 tile, BK=64 bf16, 4 waves (2x2), each wave 64x64 via 4x4 16x16x32 frags.
// LDS tiles [128 rows][128 bytes] with byte ^= ((row&7)<<4) XOR swizzle (G4);
// staged linearly via global_load_lds w16 with pre-swizzled global source (m173).
__global__ __launch_bounds__(256, 2)
void gemm_bmax_k(const unsigned short* __restrict__ Xb, const unsigned short* __restrict__ Cbb,
                 const float* __restrict__ rn, float* __restrict__ blockmax){
  __shared__ __align__(16) char As[16384];
  __shared__ __align__(16) char Bs[16384];
  const int tid  = threadIdx.x;
  const int lane = tid & 63;
  const int w    = tid >> 6;
  const int wm   = w >> 1, wn = w & 1;
  const int m0 = blockIdx.y * 128;
  const int n0 = blockIdx.x * 128;

  f32x4 acc[4][4];
  #pragma unroll
  for (int m = 0; m < 4; ++m)
    #pragma unroll
    for (int n = 0; n < 4; ++n)
      acc[m][n] = (f32x4){0.f, 0.f, 0.f, 0.f};

  for (int kt = 0; kt < 12; ++kt){
    const int k0 = kt * 64;
    #pragma unroll
    for (int i = 0; i < 4; ++i){
      const int base = w * 4096 + i * 1024;
      const int L    = base + lane * 16;
      const int row  = L >> 7;
      const int scol = (L & 127) ^ ((row & 7) << 4);
      const unsigned short* ga = Xb  + (size_t)(m0 + row) * EMB + k0 + (scol >> 1);
      const unsigned short* gb = Cbb + (size_t)(n0 + row) * EMB + k0 + (scol >> 1);
      __builtin_amdgcn_global_load_lds((const __attribute__((address_space(1))) void*)ga,
          (__attribute__((address_space(3))) void*)(As + base), 16, 0, 0);
      __builtin_amdgcn_global_load_lds((const __attribute__((address_space(1))) void*)gb,
          (__attribute__((address_space(3))) void*)(Bs + base), 16, 0, 0);
    }
    __syncthreads();
    #pragma unroll
    for (int kk = 0; kk < 2; ++kk){
      bf16x8 a[4], b[4];
      const int cb = kk * 64 + ((lane >> 4) << 4);
      #pragma unroll
      for (int m = 0; m < 4; ++m){
        const int rl = wm * 64 + m * 16 + (lane & 15);
        a[m] = *(const bf16x8*)(As + rl * 128 + (cb ^ ((rl & 7) << 4)));
      }
      #pragma unroll
      for (int n = 0; n < 4; ++n){
        const int rl = wn * 64 + n * 16 + (lane & 15);
        b[n] = *(const bf16x8*)(Bs + rl * 128 + (cb ^ ((rl & 7) << 4)));
      }
      #pragma unroll
      for (int m = 0; m < 4; ++m)
        #pragma unroll
        for (int n = 0; n < 4; ++n)
          acc[m][n] = __builtin_amdgcn_mfma_f32_16x16x32_bf16(a[m], b[n], acc[m][n], 0, 0, 0);
    }
    __syncthreads();
  }

  // epilogue: scale by rn[col], reduce 16-col max per output row, store blockmax
  float rnv[4];
  #pragma unroll
  for (int n = 0; n < 4; ++n)
    rnv[n] = rn[n0 + wn * 64 + n * 16 + (lane & 15)];
  const int rbase = m0 + wm * 64 + ((lane >> 4) << 2);
  const int bbase = (n0 >> 4) + wn * 4;
  #pragma unroll
  for (int m = 0; m < 4; ++m){
    #pragma unroll
    for (int rg = 0; rg < 4; ++rg){
      const int row = rbase + m * 16 + rg;
      #pragma unroll
      for (int n = 0; n < 4; ++n){
        float s = acc[m][n][rg] * rnv[n];
        #pragma unroll
        for (int off = 1; off < 16; off <<= 1) s = fmaxf(s, __shfl_xor(s, off));
        if ((lane & 15) == 0) blockmax[(size_t)row * NBLK + bbase + n] = s;
      }
    }
  }
}

// ---------------- per-row: select candidate blocks, fp32 rescore, write out ----
__global__ __launch_bounds__(256)
void select_write_k(const float* __restrict__ X, const float* __restrict__ Cb,
                    const float* __restrict__ rn, const float* __restrict__ blockmax,
                    float* __restrict__ out, float* __restrict__ rowloss){
  __shared__ float xs[EMB];
  __shared__ float bmx[NBLK];
  __shared__ float red[256];
  __shared__ int  redi[256];
  const int r = blockIdx.x;
  const int tid = threadIdx.x;

  for (int c = tid; c < EMB; c += 256) xs[c] = X[(size_t)r * EMB + c];
  for (int b = tid; b < NBLK; b += 256) bmx[b] = blockmax[(size_t)r * NBLK + b];
  __syncthreads();

  // global max over blockmaxes
  red[tid] = fmaxf(bmx[tid], bmx[tid + 256]);
  __syncthreads();
  for (int off = 128; off > 0; off >>= 1){
    if (tid < off) red[tid] = fmaxf(red[tid], red[tid + off]);
    __syncthreads();
  }
  const float M = red[0];
  __syncthreads();

  // rescore candidate blocks in fp32 (16 cols x 16 threads each)
  const int colg = tid >> 4;   // col within block
  const int e0   = tid & 15;
  float bval = -3.0e38f; int bidx = 0x7FFFFFFF;
  for (int b = 0; b < NBLK; ++b){
    if (bmx[b] < M - MARGIN) continue;   // uniform branch (bmx in LDS)
    const int col = b * 16 + colg;
    const float* cr = Cb + (size_t)col * EMB;
    float s = 0.f;
    for (int e = e0; e < EMB; e += 16) s = fmaf(xs[e], cr[e], s);
    #pragma unroll
    for (int off = 1; off < 16; off <<= 1) s += __shfl_xor(s, off);
    if (e0 == 0){
      s *= rn[col];
      if (s > bval){ bval = s; bidx = col; }   // strict > keeps first index
    }
  }
  red[tid]  = (e0 == 0) ? bval : -3.0e38f;
  redi[tid] = (e0 == 0) ? bidx : 0x7FFFFFFF;
  __syncthreads();
  for (int off = 128; off > 0; off >>= 1){
    if (tid < off){
      const float ov = red[tid + off]; const int oi = redi[tid + off];
      if (ov > red[tid] || (ov == red[tid] && oi < redi[tid])){ red[tid] = ov; redi[tid] = oi; }
    }
    __syncthreads();
  }
  const int idx = redi[0];

  // gather + output + per-row loss
  const float* q = Cb + (size_t)idx * EMB;
  float sl = 0.f;
  for (int c = tid; c < EMB; c += 256){
    const float qv = q[c], xv = xs[c];
    const float d = qv - xv;
    out[(size_t)r * EMB + c] = xv + d;   // matches reference arithmetic
    sl = fmaf(d, d, sl);
  }
  __syncthreads();
  red[tid] = sl; __syncthreads();
  for (int off = 128; off > 0; off >>= 1){
    if (tid < off) red[tid] += red[tid + off];
    __syncthreads();
  }
  if (tid == 0) rowloss[r] = red[0];
}

// ---------------- deterministic loss finalize ----------------
__global__ void finalize_k(const float* __restrict__ rowloss, float* __restrict__ loss_out){
  __shared__ double red[256];
  const int tid = threadIdx.x;
  double s = 0.0;
  for (int i = tid; i < NB; i += 256) s += (double)rowloss[i];
  red[tid] = s; __syncthreads();
  for (int off = 128; off > 0; off >>= 1){
    if (tid < off) red[tid] += red[tid + off];
    __syncthreads();
  }
  if (tid == 0)
    loss_out[0] = (float)(1.25 * red[0] / ((double)NB * (double)EMB));
}

extern "C" void kernel_launch(void* const* d_in, const int* in_sizes, int n_in,
                              void* d_out, int out_size, void* d_ws, size_t ws_size,
                              hipStream_t stream){
  const float* X  = (const float*)d_in[0];
  const float* Cb = (const float*)d_in[1];
  float* out = (float*)d_out;

  // bf16 staging copies live inside d_out (fully rewritten by select_write_k later)
  unsigned short* Xb  = (unsigned short*)d_out;                              // 25.2 MB
  unsigned short* Cbb = (unsigned short*)((char*)d_out + (size_t)NB*EMB*2);  // 12.6 MB

  char* ws = (char*)d_ws;
  float* blockmax = (float*)ws;                                  // 16384*512*4 = 33.55 MB
  float* rn       = (float*)(ws + (size_t)NB * NBLK * 4);        // 32 KB
  float* rowloss  = rn + NK;                                     // 64 KB

  convert_k<<<(NB * EMB / 4 + 255) / 256, 256, 0, stream>>>(X, Xb, NB * EMB / 4);
  convert_k<<<(NK * EMB / 4 + 255) / 256, 256, 0, stream>>>(Cb, Cbb, NK * EMB / 4);
  codebook_norms_k<<<NK, 256, 0, stream>>>(Cb, rn);
  gemm_bmax_k<<<dim3(NK / 128, NB / 128), 256, 0, stream>>>(Xb, Cbb, rn, blockmax);
  select_write_k<<<NB, 256, 0, stream>>>(X, Cb, rn, blockmax, out, rowloss);
  finalize_k<<<1, 256, 0, stream>>>(rowloss, out + (size_t)NB * EMB);
}

// Round 3
// 523.224 us; speedup vs baseline: 4.3904x; 1.5752x over previous
//
#include <hip/hip_runtime.h>

#define EMB 768
#define NK  8192
#define NB  16384
#define NBLK 512            // NK/16 col-blocks
#define MARGIN 0.05f        // scaled-sim margin: ~20 sigma of bf16 screening error

typedef __attribute__((ext_vector_type(8))) __bf16 bf16x8;
typedef __attribute__((ext_vector_type(4))) float f32x4;

// ---------------- fp32 -> bf16 (RTNE) ----------------
__device__ __forceinline__ unsigned short f2bf(float f){
  unsigned u = __float_as_uint(f);
  u += 0x7FFFu + ((u >> 16) & 1u);
  return (unsigned short)(u >> 16);
}

// monotonic order-preserving float<->uint encoding
__device__ __forceinline__ unsigned fenc(float v){
  unsigned u = __float_as_uint(v);
  return (u & 0x80000000u) ? ~u : (u | 0x80000000u);
}
__device__ __forceinline__ float fdec(unsigned k){
  unsigned u = (k & 0x80000000u) ? (k & 0x7FFFFFFFu) : ~k;
  return __uint_as_float(u);
}

__global__ void convert_k(const float* __restrict__ in, unsigned short* __restrict__ out, int n4){
  int i = blockIdx.x * blockDim.x + threadIdx.x;
  if (i < n4){
    float4 v = *(const float4*)(in + (size_t)i * 4);
    ushort4 o;
    o.x = f2bf(v.x); o.y = f2bf(v.y); o.z = f2bf(v.z); o.w = f2bf(v.w);
    *(ushort4*)(out + (size_t)i * 4) = o;
  }
}

// ---------------- codebook inverse norms ----------------
__global__ void codebook_norms_k(const float* __restrict__ C, float* __restrict__ rn){
  __shared__ float red[256];
  const int r = blockIdx.x;
  const int tid = threadIdx.x;
  const float* row = C + (size_t)r * EMB;
  float s = 0.f;
  for (int c = tid; c < EMB; c += 256){ float v = row[c]; s = fmaf(v, v, s); }
  red[tid] = s; __syncthreads();
  for (int off = 128; off > 0; off >>= 1){
    if (tid < off) red[tid] += red[tid + off];
    __syncthreads();
  }
  if (tid == 0){
    float n = sqrtf(red[0]);
    rn[r] = 1.0f / fmaxf(n, 1e-8f);
  }
}

// ---------------- bf16 MFMA GEMM -> transposed blockmax + rowM atomic ----------
__global__ __launch_bounds__(256, 2)
void gemm_bmax_k(const unsigned short* __restrict__ Xb, const unsigned short* __restrict__ Cbb,
                 const float* __restrict__ rn, float* __restrict__ blockmaxT,
                 unsigned* __restrict__ rowMkey){
  __shared__ __align__(16) char As[16384];
  __shared__ __align__(16) char Bs[16384];
  const int tid  = threadIdx.x;
  const int lane = tid & 63;
  const int w    = tid >> 6;
  const int wm   = w >> 1, wn = w & 1;
  const int m0 = blockIdx.y * 128;
  const int n0 = blockIdx.x * 128;

  f32x4 acc[4][4];
  #pragma unroll
  for (int m = 0; m < 4; ++m)
    #pragma unroll
    for (int n = 0; n < 4; ++n)
      acc[m][n] = (f32x4){0.f, 0.f, 0.f, 0.f};

  for (int kt = 0; kt < 12; ++kt){
    const int k0 = kt * 64;
    #pragma unroll
    for (int i = 0; i < 4; ++i){
      const int base = w * 4096 + i * 1024;
      const int L    = base + lane * 16;
      const int row  = L >> 7;
      const int scol = (L & 127) ^ ((row & 7) << 4);
      const unsigned short* ga = Xb  + (size_t)(m0 + row) * EMB + k0 + (scol >> 1);
      const unsigned short* gb = Cbb + (size_t)(n0 + row) * EMB + k0 + (scol >> 1);
      __builtin_amdgcn_global_load_lds((const __attribute__((address_space(1))) void*)ga,
          (__attribute__((address_space(3))) void*)(As + base), 16, 0, 0);
      __builtin_amdgcn_global_load_lds((const __attribute__((address_space(1))) void*)gb,
          (__attribute__((address_space(3))) void*)(Bs + base), 16, 0, 0);
    }
    __syncthreads();
    #pragma unroll
    for (int kk = 0; kk < 2; ++kk){
      bf16x8 a[4], b[4];
      const int cb = kk * 64 + ((lane >> 4) << 4);
      #pragma unroll
      for (int m = 0; m < 4; ++m){
        const int rl = wm * 64 + m * 16 + (lane & 15);
        a[m] = *(const bf16x8*)(As + rl * 128 + (cb ^ ((rl & 7) << 4)));
      }
      #pragma unroll
      for (int n = 0; n < 4; ++n){
        const int rl = wn * 64 + n * 16 + (lane & 15);
        b[n] = *(const bf16x8*)(Bs + rl * 128 + (cb ^ ((rl & 7) << 4)));
      }
      #pragma unroll
      for (int m = 0; m < 4; ++m)
        #pragma unroll
        for (int n = 0; n < 4; ++n)
          acc[m][n] = __builtin_amdgcn_mfma_f32_16x16x32_bf16(a[m], b[n], acc[m][n], 0, 0, 0);
    }
    __syncthreads();
  }

  // epilogue: scale by rn[col]; per-16col max -> blockmaxT[block][row]; rowM atomic
  float rnv[4];
  #pragma unroll
  for (int n = 0; n < 4; ++n)
    rnv[n] = rn[n0 + wn * 64 + n * 16 + (lane & 15)];
  const int rbase = m0 + wm * 64 + ((lane >> 4) << 2);
  const int bbase = (n0 >> 4) + wn * 4;
  #pragma unroll
  for (int m = 0; m < 4; ++m){
    #pragma unroll
    for (int rg = 0; rg < 4; ++rg){
      const int row = rbase + m * 16 + rg;
      float wmax = -3.0e38f;
      #pragma unroll
      for (int n = 0; n < 4; ++n){
        float s = acc[m][n][rg] * rnv[n];
        #pragma unroll
        for (int off = 1; off < 16; off <<= 1) s = fmaxf(s, __shfl_xor(s, off));
        if ((lane & 15) == 0) blockmaxT[(size_t)(bbase + n) * NB + row] = s;
        wmax = fmaxf(wmax, s);
      }
      if ((lane & 15) == 0) atomicMax(&rowMkey[row], fenc(wmax));
    }
  }
}

// ---------------- codebook-stationary fp32 rescore ----------------
// One wg per 16-col block: codebook block in LDS; scan blockmaxT[b][*] coalesced;
// candidate rows rescored by one wave each; packed-key atomicMax combine.
__global__ __launch_bounds__(256)
void rescore_k(const float* __restrict__ X, const float* __restrict__ Cb,
               const float* __restrict__ rn, const float* __restrict__ blockmaxT,
               const unsigned* __restrict__ rowMkey, unsigned long long* __restrict__ keys){
  __shared__ float cbs[16 * EMB];   // 48 KB
  __shared__ float rns[16];
  __shared__ int cand[1024];
  __shared__ int ncand;
  const int b = blockIdx.x;
  const int tid = threadIdx.x;
  const int lane = tid & 63;
  const int w = tid >> 6;

  for (int i = tid; i < 16 * EMB / 4; i += 256)
    ((float4*)cbs)[i] = ((const float4*)(Cb + (size_t)b * 16 * EMB))[i];
  if (tid < 16) rns[tid] = rn[b * 16 + tid];

  const float* bm = blockmaxT + (size_t)b * NB;
  for (int r0 = 0; r0 < NB; r0 += 1024){
    __syncthreads();
    if (tid == 0) ncand = 0;
    __syncthreads();
    #pragma unroll
    for (int k = 0; k < 4; ++k){
      const int r = r0 + k * 256 + tid;
      const float v = bm[r];
      const float M = fdec(rowMkey[r]);
      if (v >= M - MARGIN){
        int slot = atomicAdd(&ncand, 1);
        cand[slot] = r;           // slot < 1024 by construction
      }
    }
    __syncthreads();
    const int nc = ncand;
    for (int ci = w; ci < nc; ci += 4){
      const int r = cand[ci];
      const float* xr = X + (size_t)r * EMB;
      float x[12];
      #pragma unroll
      for (int j = 0; j < 12; ++j) x[j] = xr[lane + 64 * j];
      float best = -3.0e38f; int bc = 0;
      #pragma unroll
      for (int c = 0; c < 16; ++c){
        float s = 0.f;
        #pragma unroll
        for (int j = 0; j < 12; ++j) s = fmaf(x[j], cbs[c * EMB + lane + 64 * j], s);
        #pragma unroll
        for (int off = 1; off < 64; off <<= 1) s += __shfl_xor(s, off);
        s *= rns[c];
        if (s > best){ best = s; bc = c; }     // strict > : first index within block
      }
      if (lane == 0){
        const int col = b * 16 + bc;
        const unsigned long long key =
            ((unsigned long long)fenc(best) << 32) | (unsigned)(8191 - col);
        atomicMax(&keys[r], key);
      }
    }
  }
}

// ---------------- gather + output + per-row loss ----------------
__global__ void writer_k(const float* __restrict__ X, const float* __restrict__ Cb,
                         const unsigned long long* __restrict__ keys,
                         float* __restrict__ out, float* __restrict__ rowloss){
  __shared__ float red[256];
  const int r = blockIdx.x;
  const int tid = threadIdx.x;
  const int idx = 8191 - (int)(unsigned)(keys[r] & 0xFFFFFFFFull);
  const float* q = Cb + (size_t)idx * EMB;
  const float* x = X + (size_t)r * EMB;
  float* o = out + (size_t)r * EMB;
  float s = 0.f;
  for (int c = tid; c < EMB; c += 256){
    const float qv = q[c], xv = x[c];
    const float d = qv - xv;
    o[c] = xv + d;
    s = fmaf(d, d, s);
  }
  red[tid] = s; __syncthreads();
  for (int off = 128; off > 0; off >>= 1){
    if (tid < off) red[tid] += red[tid + off];
    __syncthreads();
  }
  if (tid == 0) rowloss[r] = red[0];
}

// ---------------- deterministic loss finalize ----------------
__global__ void finalize_k(const float* __restrict__ rowloss, float* __restrict__ loss_out){
  __shared__ double red[256];
  const int tid = threadIdx.x;
  double s = 0.0;
  for (int i = tid; i < NB; i += 256) s += (double)rowloss[i];
  red[tid] = s; __syncthreads();
  for (int off = 128; off > 0; off >>= 1){
    if (tid < off) red[tid] += red[tid + off];
    __syncthreads();
  }
  if (tid == 0)
    loss_out[0] = (float)(1.25 * red[0] / ((double)NB * (double)EMB));
}

extern "C" void kernel_launch(void* const* d_in, const int* in_sizes, int n_in,
                              void* d_out, int out_size, void* d_ws, size_t ws_size,
                              hipStream_t stream){
  const float* X  = (const float*)d_in[0];
  const float* Cb = (const float*)d_in[1];
  float* out = (float*)d_out;

  // bf16 staging copies live inside d_out (fully rewritten by writer_k later)
  unsigned short* Xb  = (unsigned short*)d_out;                              // 25.2 MB
  unsigned short* Cbb = (unsigned short*)((char*)d_out + (size_t)NB*EMB*2);  // 12.6 MB

  char* ws = (char*)d_ws;
  float* blockmaxT = (float*)ws;                                       // 33.55 MB
  char*  p = ws + (size_t)NBLK * NB * 4;
  unsigned* rowMkey = (unsigned*)p;            p += (size_t)NB * 4;    // 64 KB
  unsigned long long* keys = (unsigned long long*)p; p += (size_t)NB * 8; // 128 KB
  float* rn      = (float*)p;                  p += (size_t)NK * 4;    // 32 KB
  float* rowloss = (float*)p;                                          // 64 KB

  hipMemsetAsync(rowMkey, 0, (size_t)NB * 4, stream);
  hipMemsetAsync(keys, 0, (size_t)NB * 8, stream);
  convert_k<<<(NB * EMB / 4 + 255) / 256, 256, 0, stream>>>(X, Xb, NB * EMB / 4);
  convert_k<<<(NK * EMB / 4 + 255) / 256, 256, 0, stream>>>(Cb, Cbb, NK * EMB / 4);
  codebook_norms_k<<<NK, 256, 0, stream>>>(Cb, rn);
  gemm_bmax_k<<<dim3(NK / 128, NB / 128), 256, 0, stream>>>(Xb, Cbb, rn, blockmaxT, rowMkey);
  rescore_k<<<NBLK, 256, 0, stream>>>(X, Cb, rn, blockmaxT, rowMkey, keys);
  writer_k<<<NB, 256, 0, stream>>>(X, Cb, keys, out, rowloss);
  finalize_k<<<1, 256, 0, stream>>>(rowloss, out + (size_t)NB * EMB);
}